// Round 4
// baseline (1198.245 us; speedup 1.0000x reference)
//
#include <hip/hip_runtime.h>
#include <hip/hip_bf16.h>

typedef unsigned short u16;
typedef unsigned int u32;
typedef __bf16 bf16x8 __attribute__((ext_vector_type(8)));
typedef float f32x4 __attribute__((ext_vector_type(4)));

#define NTOK 524288      // B*H*W tokens
#define NWIN 8192        // B * 1024 windows
#define SCALE 0.20412414523193154f   // 24^-0.5

__device__ inline u16 f2bf(float f) {
    __hip_bfloat16 h = __float2bfloat16(f);
    return __builtin_bit_cast(u16, h);
}
__device__ inline float bf2f(u16 u) {
    return __bfloat162float(__builtin_bit_cast(__hip_bfloat16, u));
}
__device__ inline bf16x8 ldfrag(const u16* p) {
    return __builtin_bit_cast(bf16x8, *reinterpret_cast<const int4*>(p));
}
__device__ inline bf16x8 zfrag() {
    return __builtin_bit_cast(bf16x8, make_int4(0, 0, 0, 0));
}
// fast erf-GELU: Abramowitz&Stegun 7.1.26, |err|<=1.5e-7 (invisible in bf16)
__device__ inline float gelu_f(float v) {
    float x  = v * 0.70710678118654752f;
    float ax = fabsf(x);
    float t  = __builtin_amdgcn_rcpf(fmaf(0.3275911f, ax, 1.0f));
    float y  = t * fmaf(t, fmaf(t, fmaf(t, fmaf(t, 1.061405429f, -1.453152027f),
                                        1.421413741f), -0.284496736f), 0.254829592f);
    float er = 1.0f - y * __expf(-ax * ax);
    er = (x < 0.0f) ? -er : er;
    return 0.5f * v * (1.0f + er);
}
__device__ inline int region_of(int wh, int ww, int n) {
    int hr = wh * 8 + (n >> 3);
    int wc = ww * 8 + (n & 7);
    int rh = (hr < 248) ? 0 : (hr < 252 ? 1 : 2);
    int rw = (wc < 248) ? 0 : (wc < 252 ? 1 : 2);
    return rh * 3 + rw;
}

// ---------------- kernel 0: weight convert/transpose to bf16, LN-gamma folded ----------------
// qkvT:[288][96] = g1[k]*qkv_w (q cols pre-scaled)   projT:[96][96]
// w1T:[384][96] = g2[k]*w1                           w2T:[96][384]
__global__ __launch_bounds__(256) void k_convert(
        const float* __restrict__ qkv_w, const float* __restrict__ proj_w,
        const float* __restrict__ w1, const float* __restrict__ w2,
        const float* __restrict__ n1g, const float* __restrict__ n2g,
        u16* __restrict__ qkvT, u16* __restrict__ projT,
        u16* __restrict__ w1T, u16* __restrict__ w2T) {
    int idx = blockIdx.x * 256 + threadIdx.x;
    if (idx < 288 * 96) {
        int n = idx / 96, k = idx % 96;
        float v = qkv_w[k * 288 + n] * n1g[k];
        if (n < 96) v *= SCALE;
        qkvT[n * 96 + k] = f2bf(v);
    }
    if (idx < 96 * 96) {
        int n = idx / 96, k = idx % 96;
        projT[n * 96 + k] = f2bf(proj_w[k * 96 + n]);
    }
    if (idx < 384 * 96) {
        int n = idx / 96, k = idx % 96;
        w1T[n * 96 + k] = f2bf(w1[k * 384 + n] * n2g[k]);
    }
    if (idx < 96 * 384) {
        int n = idx / 384, k = idx % 384;
        w2T[n * 384 + k] = f2bf(w2[k * 96 + n]);
    }
}

// ---------------- kernel 1: QKV GEMM with fused LN1 + roll + window partition ----------------
// Reads x directly (roll-mapped rows). Per row: raw LN (affine folded into weights/bias).
// A-frag lanes of one row live in the 4 quads -> cross-quad shfl_xor gives row stats.
// Bias fold: qb[n] = (qkv_b[n] + sum_k n1b[k]*qkv_w[k][n]) * (n<96?SCALE:1), computed
// per block from L2-resident qkv_w (27k fma, overlaps weight staging).
__global__ __launch_bounds__(256) void k_qkv(const float* __restrict__ x,
                                             const u16* __restrict__ wT,
                                             const float* __restrict__ qkv_wf,
                                             const float* __restrict__ qkv_b,
                                             const float* __restrict__ n1b,
                                             u16* __restrict__ qkv) {
    __shared__ __align__(16) u16 wlds[288 * 104];   // padded stride 104
    __shared__ float qb[288];
    {
        const int4* src = reinterpret_cast<const int4*>(wT);
        for (int i = threadIdx.x; i < 288 * 12; i += 256) {
            int row = i / 12, j = i - row * 12;
            *reinterpret_cast<int4*>(&wlds[row * 104 + j * 8]) = src[i];
        }
        for (int n = threadIdx.x; n < 288; n += 256) {
            float s = qkv_b[n];
#pragma unroll 8
            for (int k = 0; k < 96; k++) s = fmaf(n1b[k], qkv_wf[k * 288 + n], s);
            qb[n] = (n < 96) ? s * SCALE : s;
        }
    }
    __syncthreads();
    const int wave = threadIdx.x >> 6, lane = threadIdx.x & 63;
    const int l15 = lane & 15, quad = lane >> 4;
    const int rowbase = blockIdx.x * 128 + wave * 32;
    // fused LN1: build A-frags in registers
    bf16x8 afr[2][3];
#pragma unroll
    for (int m = 0; m < 2; m++) {
        int wtok = rowbase + m * 16 + l15;
        int win = wtok >> 6, n = wtok & 63;
        int b_ = win >> 10, wh = (win >> 5) & 31, ww = win & 31;
        int h0 = (wh * 8 + (n >> 3) + 4) & 255;
        int w0 = (ww * 8 + (n & 7) + 4) & 255;
        const float* row = x + ((size_t)(b_ * 256 + h0) * 256 + w0) * 96;
        float v[3][8];
        float s = 0.f, q = 0.f;
#pragma unroll
        for (int kb = 0; kb < 3; kb++) {
            f32x4 p0 = *reinterpret_cast<const f32x4*>(row + kb * 32 + quad * 8);
            f32x4 p1 = *reinterpret_cast<const f32x4*>(row + kb * 32 + quad * 8 + 4);
#pragma unroll
            for (int j = 0; j < 4; j++) { v[kb][j] = p0[j]; v[kb][4 + j] = p1[j]; }
#pragma unroll
            for (int j = 0; j < 8; j++) { s += v[kb][j]; q += v[kb][j] * v[kb][j]; }
        }
        s += __shfl_xor(s, 16); q += __shfl_xor(q, 16);
        s += __shfl_xor(s, 32); q += __shfl_xor(q, 32);
        float mean = s * (1.0f / 96.0f);
        float var  = q * (1.0f / 96.0f) - mean * mean;
        float rstd = rsqrtf(var + 1e-5f);
#pragma unroll
        for (int kb = 0; kb < 3; kb++) {
            union { bf16x8 f; u16 u[8]; } pk;
#pragma unroll
            for (int j = 0; j < 8; j++) pk.u[j] = f2bf((v[kb][j] - mean) * rstd);
            afr[m][kb] = pk.f;
        }
    }
    f32x4 zero = {0.f, 0.f, 0.f, 0.f};
    f32x4 acc[2][18];
#pragma unroll
    for (int mt = 0; mt < 2; mt++)
#pragma unroll
        for (int ct = 0; ct < 18; ct++) acc[mt][ct] = zero;
#pragma unroll
    for (int kb = 0; kb < 3; kb++) {
#pragma unroll
        for (int ct = 0; ct < 18; ct++) {
            bf16x8 bf = ldfrag(&wlds[(ct * 16 + l15) * 104 + kb * 32 + quad * 8]);
            acc[0][ct] = __builtin_amdgcn_mfma_f32_16x16x32_bf16(afr[0][kb], bf, acc[0][ct], 0, 0, 0);
            acc[1][ct] = __builtin_amdgcn_mfma_f32_16x16x32_bf16(afr[1][kb], bf, acc[1][ct], 0, 0, 0);
        }
    }
#pragma unroll
    for (int mt = 0; mt < 2; mt++)
#pragma unroll
        for (int ct = 0; ct < 18; ct++) {
            int col = ct * 16 + l15;
            float bv = qb[col];
#pragma unroll
            for (int r = 0; r < 4; r++) {
                int row = rowbase + mt * 16 + quad * 4 + r;
                qkv[(size_t)row * 288 + col] = f2bf(acc[mt][ct][r] + bv);
            }
        }
}

// ---------------- kernel 2: windowed attention (1 block/window, 1 wave/head) ----------------
__global__ __launch_bounds__(256) void k_attn(const u16* __restrict__ qkv,
                                              const float* __restrict__ btab,
                                              u16* __restrict__ aout) {
    __shared__ __align__(16) float blds[900];
    __shared__ __align__(16) u16 vt[4][24 * 72];   // V^T per head, padded stride 72
    __shared__ __align__(16) u16 pm[4][64 * 72];   // P per head, padded stride 72
    const int tid = threadIdx.x;
    for (int i = tid; i < 900; i += 256)
        blds[i] = fminf(fmaxf(btab[i], -5.0f), 5.0f);
    const int head = tid >> 6, lane = tid & 63;
    const int l15 = lane & 15, quad = lane >> 4;
    const int win = blockIdx.x;
    const int wh = (win >> 5) & 31, ww = win & 31;
    const u16* base = qkv + (size_t)win * 64 * 288;
    // stage V^T: vt[head][d][tok]
#pragma unroll
    for (int it = 0; it < 3; it++) {
        int idx = it * 64 + lane;
        int tok = idx / 3, ch = idx - tok * 3;
        int4 raw = *reinterpret_cast<const int4*>(base + tok * 288 + 192 + head * 24 + ch * 8);
        union { int4 v; u16 u[8]; } uu; uu.v = raw;
#pragma unroll
        for (int j = 0; j < 8; j++) vt[head][(ch * 8 + j) * 72 + tok] = uu.u[j];
    }
    __syncthreads();
    // Q (A-op) and K (B-op) fragments; K-dim 24 padded to 32 (quad 3 = zeros)
    bf16x8 aq[4], bk[4];
#pragma unroll
    for (int t = 0; t < 4; t++) {
        if (quad < 3) {
            aq[t] = ldfrag(base + (t * 16 + l15) * 288 + head * 24 + quad * 8);
            bk[t] = ldfrag(base + (t * 16 + l15) * 288 + 96 + head * 24 + quad * 8);
        } else { aq[t] = zfrag(); bk[t] = zfrag(); }
    }
    f32x4 zero = {0.f, 0.f, 0.f, 0.f};
    f32x4 s[4][4];
#pragma unroll
    for (int mt = 0; mt < 4; mt++)
#pragma unroll
        for (int ct = 0; ct < 4; ct++)
            s[mt][ct] = __builtin_amdgcn_mfma_f32_16x16x32_bf16(aq[mt], bk[ct], zero, 0, 0, 0);
    // per-column region ids for this lane
    int regc[4], colr[4], colc[4];
#pragma unroll
    for (int ct = 0; ct < 4; ct++) {
        int col = ct * 16 + l15;
        colr[ct] = col >> 3; colc[ct] = col & 7;
        regc[ct] = region_of(wh, ww, col);
    }
    // mask + bias + clip + row softmax (rows live in 16-lane groups)
#pragma unroll
    for (int mt = 0; mt < 4; mt++) {
#pragma unroll
        for (int r = 0; r < 4; r++) {
            int row = mt * 16 + quad * 4 + r;
            int rr = row >> 3, rc = row & 7;
            int regr = region_of(wh, ww, row);
            float sv[4]; float mx = -1e30f;
#pragma unroll
            for (int ct = 0; ct < 4; ct++) {
                float bias = blds[((rr - colr[ct] + 7) * 15 + (rc - colc[ct] + 7)) * 4 + head];
                float v = (regr == regc[ct])
                        ? fminf(fmaxf(s[mt][ct][r] + bias, -10.0f), 10.0f) : -10.0f;
                sv[ct] = v; mx = fmaxf(mx, v);
            }
#pragma unroll
            for (int m = 1; m < 16; m <<= 1) mx = fmaxf(mx, __shfl_xor(mx, m));
            float sum = 0.f;
#pragma unroll
            for (int ct = 0; ct < 4; ct++) { sv[ct] = __expf(sv[ct] - mx); sum += sv[ct]; }
#pragma unroll
            for (int m = 1; m < 16; m <<= 1) sum += __shfl_xor(sum, m);
            float inv = 1.0f / sum;
#pragma unroll
            for (int ct = 0; ct < 4; ct++)
                pm[head][row * 72 + ct * 16 + l15] = f2bf(sv[ct] * inv);
        }
    }
    __syncthreads();
    // O = P @ V
    f32x4 o[4][2];
#pragma unroll
    for (int mt = 0; mt < 4; mt++) { o[mt][0] = zero; o[mt][1] = zero; }
#pragma unroll
    for (int kb = 0; kb < 2; kb++) {
        bf16x8 ap[4];
#pragma unroll
        for (int mt = 0; mt < 4; mt++)
            ap[mt] = ldfrag(&pm[head][(mt * 16 + l15) * 72 + kb * 32 + quad * 8]);
        bf16x8 bv0 = ldfrag(&vt[head][l15 * 72 + kb * 32 + quad * 8]);
        bf16x8 bv1 = (l15 < 8) ? ldfrag(&vt[head][(16 + l15) * 72 + kb * 32 + quad * 8]) : zfrag();
#pragma unroll
        for (int mt = 0; mt < 4; mt++) {
            o[mt][0] = __builtin_amdgcn_mfma_f32_16x16x32_bf16(ap[mt], bv0, o[mt][0], 0, 0, 0);
            o[mt][1] = __builtin_amdgcn_mfma_f32_16x16x32_bf16(ap[mt], bv1, o[mt][1], 0, 0, 0);
        }
    }
#pragma unroll
    for (int ct2 = 0; ct2 < 2; ct2++) {
        int d = ct2 * 16 + l15;
        if (d < 24) {
#pragma unroll
            for (int mt = 0; mt < 4; mt++)
#pragma unroll
                for (int r = 0; r < 4; r++) {
                    int tok = mt * 16 + quad * 4 + r;
                    aout[((size_t)win * 64 + tok) * 96 + head * 24 + d] = f2bf(o[mt][ct2][r]);
                }
        }
    }
}

// ------- kernel 3: proj GEMM + window reverse + roll(+4,+4) + residual -> x1b (bf16) -------
// (LN2 moved into k_mlp; hnb deleted)
__global__ __launch_bounds__(256) void k_proj(const u16* __restrict__ aout,
                                              const u16* __restrict__ wT,
                                              const float* __restrict__ pb,
                                              const float* __restrict__ x,
                                              u16* __restrict__ x1b) {
    __shared__ __align__(16) u16 wlds[96 * 104];
    {
        const int4* src = reinterpret_cast<const int4*>(wT);
        for (int i = threadIdx.x; i < 96 * 12; i += 256) {
            int row = i / 12, j = i - row * 12;
            *reinterpret_cast<int4*>(&wlds[row * 104 + j * 8]) = src[i];
        }
    }
    __syncthreads();
    const int wave = threadIdx.x >> 6, lane = threadIdx.x & 63;
    const int l15 = lane & 15, quad = lane >> 4;
    const int rowbase = blockIdx.x * 128 + wave * 32;
    f32x4 zero = {0.f, 0.f, 0.f, 0.f};
    f32x4 acc[2][6];
#pragma unroll
    for (int mt = 0; mt < 2; mt++)
#pragma unroll
        for (int ct = 0; ct < 6; ct++) acc[mt][ct] = zero;
#pragma unroll
    for (int kb = 0; kb < 96; kb += 32) {
        bf16x8 a0 = ldfrag(aout + (size_t)(rowbase + l15) * 96 + kb + quad * 8);
        bf16x8 a1 = ldfrag(aout + (size_t)(rowbase + 16 + l15) * 96 + kb + quad * 8);
#pragma unroll
        for (int ct = 0; ct < 6; ct++) {
            bf16x8 bf = ldfrag(&wlds[(ct * 16 + l15) * 104 + kb + quad * 8]);
            acc[0][ct] = __builtin_amdgcn_mfma_f32_16x16x32_bf16(a0, bf, acc[0][ct], 0, 0, 0);
            acc[1][ct] = __builtin_amdgcn_mfma_f32_16x16x32_bf16(a1, bf, acc[1][ct], 0, 0, 0);
        }
    }
    float pbv[6];
#pragma unroll
    for (int ct = 0; ct < 6; ct++) pbv[ct] = pb[ct * 16 + l15];
#pragma unroll
    for (int mt = 0; mt < 2; mt++)
#pragma unroll
        for (int r = 0; r < 4; r++) {
            int wtok = rowbase + mt * 16 + quad * 4 + r;
            int win = wtok >> 6, n = wtok & 63;
            int b_ = win >> 10, wh = (win >> 5) & 31, ww = win & 31;
            int h0 = (wh * 8 + (n >> 3) + 4) & 255;
            int w0 = (ww * 8 + (n & 7) + 4) & 255;
            size_t obase = ((size_t)(b_ * 256 + h0) * 256 + w0) * 96;
#pragma unroll
            for (int ct = 0; ct < 6; ct++) {
                size_t o = obase + ct * 16 + l15;
                x1b[o] = f2bf(acc[mt][ct][r] + pbv[ct] + x[o]);
            }
        }
}

// ------- kernel 4: fused MLP with in-register LN2, 16 waves, shuffle handoff -------
// LN2 affine folded: w1T pre-multiplied by g2; b1l[n] = b1[n] + sum_k n2b[k]*w1[k][n]
// (computed per block from L2-resident w1). A-frags (raw-normalized x1) register-resident
// across the whole kc loop -> x1 read ONCE per g. No barriers in main loop.
__global__ __launch_bounds__(1024) void k_mlp(const u16* __restrict__ x1,
                                              const float* __restrict__ b1,
                                              const float* __restrict__ n2b,
                                              const float* __restrict__ w1f,
                                              const u16* __restrict__ w1T,
                                              const u16* __restrict__ w2T,
                                              const float* __restrict__ b2,
                                              float* __restrict__ out) {
    __shared__ __align__(16) u16 w1l[384 * 104];   // 79872 B
    __shared__ __align__(16) u16 w2l[96 * 392];    // 75264 B
    __shared__ __align__(16) float b1l[384];       // 1536 B
    const int tid = threadIdx.x;
    {
        const int4* s1 = reinterpret_cast<const int4*>(w1T);
        for (int i = tid; i < 384 * 12; i += 1024) {
            int row = i / 12, j = i - row * 12;
            *reinterpret_cast<int4*>(&w1l[row * 104 + j * 8]) = s1[i];
        }
        const int4* s2 = reinterpret_cast<const int4*>(w2T);
        for (int i = tid; i < 96 * 48; i += 1024) {
            int row = i / 48, j = i - row * 48;
            *reinterpret_cast<int4*>(&w2l[row * 392 + j * 8]) = s2[i];
        }
        if (tid < 384) {
            float s = b1[tid];
#pragma unroll 8
            for (int k = 0; k < 96; k++) s = fmaf(n2b[k], w1f[k * 384 + tid], s);
            b1l[tid] = s;
        }
    }
    __syncthreads();   // the ONLY barrier
    const int wave = tid >> 6, lane = tid & 63;
    const int l15 = lane & 15, quad = lane >> 4;
    const int sA = ((lane & 16) << 1) + l15;
    const int sB = sA + 16;
    const bool useHi = (lane & 32) != 0;
    const f32x4 zero = {0.f, 0.f, 0.f, 0.f};
    float b2v[6];
#pragma unroll
    for (int ct2 = 0; ct2 < 6; ct2++) b2v[ct2] = b2[ct2 * 16 + l15];
#pragma unroll 1
    for (int g = 0; g < 4; ++g) {
        const int tok0 = blockIdx.x * 2048 + g * 512 + wave * 32;
        // in-register LN2 -> A-frags for gemm1 (held across the whole kc loop)
        bf16x8 a1[2][3];
#pragma unroll
        for (int m = 0; m < 2; m++) {
            const u16* rp = x1 + (size_t)(tok0 + m * 16 + l15) * 96;
            float v[3][8];
            float s = 0.f, q = 0.f;
#pragma unroll
            for (int kb = 0; kb < 3; kb++) {
                union { int4 i; u16 u[8]; } raw;
                raw.i = *reinterpret_cast<const int4*>(rp + kb * 32 + quad * 8);
#pragma unroll
                for (int j = 0; j < 8; j++) {
                    float f = bf2f(raw.u[j]);
                    v[kb][j] = f; s += f; q += f * f;
                }
            }
            s += __shfl_xor(s, 16); q += __shfl_xor(q, 16);
            s += __shfl_xor(s, 32); q += __shfl_xor(q, 32);
            float mean = s * (1.0f / 96.0f);
            float var  = q * (1.0f / 96.0f) - mean * mean;
            float rstd = rsqrtf(var + 1e-5f);
#pragma unroll
            for (int kb = 0; kb < 3; kb++) {
                union { bf16x8 f; u16 u[8]; } pk;
#pragma unroll
                for (int j = 0; j < 8; j++) pk.u[j] = f2bf((v[kb][j] - mean) * rstd);
                a1[m][kb] = pk.f;
            }
        }
        f32x4 acc2[2][6];
#pragma unroll
        for (int m = 0; m < 2; m++)
#pragma unroll
            for (int ct2 = 0; ct2 < 6; ct2++) acc2[m][ct2] = zero;
#pragma unroll 1
        for (int kc = 0; kc < 12; ++kc) {
            bf16x8 bw2[6];
#pragma unroll
            for (int ct2 = 0; ct2 < 6; ct2++)
                bw2[ct2] = ldfrag(&w2l[(ct2 * 16 + l15) * 392 + kc * 32 + quad * 8]);
            f32x4 bia0 = *reinterpret_cast<const f32x4*>(&b1l[kc * 32 + quad * 4]);
            f32x4 bia1 = *reinterpret_cast<const f32x4*>(&b1l[kc * 32 + 16 + quad * 4]);
            // gemm1 (swapped): D[h][t], lane holds t = l15, regs r -> h = kc*32 + ct*16 + quad*4 + r
            f32x4 acc1[2][2];
#pragma unroll
            for (int m = 0; m < 2; m++) { acc1[m][0] = zero; acc1[m][1] = zero; }
#pragma unroll
            for (int kb = 0; kb < 3; kb++) {
                bf16x8 wb0 = ldfrag(&w1l[(kc * 32 + l15) * 104 + kb * 32 + quad * 8]);
                bf16x8 wb1 = ldfrag(&w1l[(kc * 32 + 16 + l15) * 104 + kb * 32 + quad * 8]);
                acc1[0][0] = __builtin_amdgcn_mfma_f32_16x16x32_bf16(wb0, a1[0][kb], acc1[0][0], 0, 0, 0);
                acc1[0][1] = __builtin_amdgcn_mfma_f32_16x16x32_bf16(wb1, a1[0][kb], acc1[0][1], 0, 0, 0);
                acc1[1][0] = __builtin_amdgcn_mfma_f32_16x16x32_bf16(wb0, a1[1][kb], acc1[1][0], 0, 0, 0);
                acc1[1][1] = __builtin_amdgcn_mfma_f32_16x16x32_bf16(wb1, a1[1][kb], acc1[1][1], 0, 0, 0);
            }
#pragma unroll
            for (int m = 0; m < 2; m++) {
                // bias + GELU, pack (ct0, ct1) pairs into u32
                u32 p[4];
#pragma unroll
                for (int r = 0; r < 4; r++) {
                    float g0 = gelu_f(acc1[m][0][r] + bia0[r]);
                    float g1 = gelu_f(acc1[m][1][r] + bia1[r]);
                    p[r] = (u32)f2bf(g0) | ((u32)f2bf(g1) << 16);
                }
                // regroup to gemm2 A-layout: af[j] = H[t][kc*32 + quad*8 + j]
                u32 shl[4], shh[4];
#pragma unroll
                for (int r = 0; r < 4; r++) {
                    shl[r] = (u32)__shfl((int)p[r], sA);
                    shh[r] = (u32)__shfl((int)p[r], sB);
                }
                u32 aw[4];
                aw[0] = useHi ? ((shl[0] >> 16) | (shl[1] & 0xffff0000u))
                              : ((shl[0] & 0xffffu) | (shl[1] << 16));
                aw[1] = useHi ? ((shl[2] >> 16) | (shl[3] & 0xffff0000u))
                              : ((shl[2] & 0xffffu) | (shl[3] << 16));
                aw[2] = useHi ? ((shh[0] >> 16) | (shh[1] & 0xffff0000u))
                              : ((shh[0] & 0xffffu) | (shh[1] << 16));
                aw[3] = useHi ? ((shh[2] >> 16) | (shh[3] & 0xffff0000u))
                              : ((shh[2] & 0xffffu) | (shh[3] << 16));
                bf16x8 a2 = __builtin_bit_cast(bf16x8, *reinterpret_cast<uint4*>(aw));
#pragma unroll
                for (int ct2 = 0; ct2 < 6; ct2++)
                    acc2[m][ct2] = __builtin_amdgcn_mfma_f32_16x16x32_bf16(a2, bw2[ct2], acc2[m][ct2], 0, 0, 0);
            }
        }
        // epilogue: +b2, +residual, f32 store
#pragma unroll
        for (int m = 0; m < 2; m++)
#pragma unroll
            for (int ct2 = 0; ct2 < 6; ct2++)
#pragma unroll
                for (int r = 0; r < 4; r++) {
                    size_t o = (size_t)(tok0 + m * 16 + quad * 4 + r) * 96 + ct2 * 16 + l15;
                    out[o] = acc2[m][ct2][r] + b2v[ct2] + bf2f(x1[o]);
                }
    }
}

extern "C" void kernel_launch(void* const* d_in, const int* in_sizes, int n_in,
                              void* d_out, int out_size, void* d_ws, size_t ws_size,
                              hipStream_t stream) {
    const float* x      = (const float*)d_in[0];
    const float* n1g    = (const float*)d_in[1];
    const float* n1b    = (const float*)d_in[2];
    const float* qkv_w  = (const float*)d_in[3];
    const float* qkv_b  = (const float*)d_in[4];
    const float* btab   = (const float*)d_in[5];
    const float* proj_w = (const float*)d_in[6];
    const float* proj_b = (const float*)d_in[7];
    const float* n2g    = (const float*)d_in[8];
    const float* n2b    = (const float*)d_in[9];
    const float* w1     = (const float*)d_in[10];
    const float* b1     = (const float*)d_in[11];
    const float* w2     = (const float*)d_in[12];
    const float* b2     = (const float*)d_in[13];
    float* out = (float*)d_out;
    char* ws = (char*)d_ws;

    // region 0 (0..302MB): qkvb during qkv/attn phase; then x1b (bf16) after
    u16* qkvb  = (u16*)(ws);                  // 524288*288*2 = 301,989,888
    u16* x1b   = (u16*)(ws);                  // 100,663,296 (reuses qkvb after attn)
    u16* tokb  = (u16*)(ws + 301989888);      // 100,663,296 (attn out)
    u16* qkvT  = (u16*)(ws + 402653184);      // 288*96*2 = 55,296
    u16* projT = (u16*)(ws + 402708480);      // 96*96*2  = 18,432
    u16* w1T   = (u16*)(ws + 402726912);      // 384*96*2 = 73,728
    u16* w2T   = (u16*)(ws + 402800640);      // 96*384*2 = 73,728 (end 402,874,368)

    k_convert<<<144, 256, 0, stream>>>(qkv_w, proj_w, w1, w2, n1g, n2g, qkvT, projT, w1T, w2T);
    k_qkv<<<NTOK / 128, 256, 0, stream>>>(x, qkvT, qkv_w, qkv_b, n1b, qkvb);
    k_attn<<<NWIN, 256, 0, stream>>>(qkvb, btab, tokb);
    k_proj<<<NTOK / 128, 256, 0, stream>>>(tokb, projT, proj_b, x, x1b);
    k_mlp<<<256, 1024, 0, stream>>>(x1b, b1, n2b, w1, w1T, w2T, b2, out);
}

// Round 5
// 1030.012 us; speedup vs baseline: 1.1633x; 1.1633x over previous
//
#include <hip/hip_runtime.h>
#include <hip/hip_bf16.h>

typedef unsigned short u16;
typedef unsigned int u32;
typedef __bf16 bf16x8 __attribute__((ext_vector_type(8)));
typedef float f32x4 __attribute__((ext_vector_type(4)));

#define NTOK 524288      // B*H*W tokens
#define NWIN 8192        // B * 1024 windows
#define SCALE 0.20412414523193154f   // 24^-0.5

__device__ inline u16 f2bf(float f) {
    __hip_bfloat16 h = __float2bfloat16(f);
    return __builtin_bit_cast(u16, h);
}
__device__ inline float bf2f(u16 u) {
    return __bfloat162float(__builtin_bit_cast(__hip_bfloat16, u));
}
__device__ inline bf16x8 ldfrag(const u16* p) {
    return __builtin_bit_cast(bf16x8, *reinterpret_cast<const int4*>(p));
}
__device__ inline bf16x8 zfrag() {
    return __builtin_bit_cast(bf16x8, make_int4(0, 0, 0, 0));
}
// fast erf-GELU: Abramowitz&Stegun 7.1.26, |err|<=1.5e-7 (invisible in bf16)
__device__ inline float gelu_f(float v) {
    float x  = v * 0.70710678118654752f;
    float ax = fabsf(x);
    float t  = __builtin_amdgcn_rcpf(fmaf(0.3275911f, ax, 1.0f));
    float y  = t * fmaf(t, fmaf(t, fmaf(t, fmaf(t, 1.061405429f, -1.453152027f),
                                        1.421413741f), -0.284496736f), 0.254829592f);
    float er = 1.0f - y * __expf(-ax * ax);
    er = (x < 0.0f) ? -er : er;
    return 0.5f * v * (1.0f + er);
}
__device__ inline int region_of(int wh, int ww, int n) {
    int hr = wh * 8 + (n >> 3);
    int wc = ww * 8 + (n & 7);
    int rh = (hr < 248) ? 0 : (hr < 252 ? 1 : 2);
    int rw = (wc < 248) ? 0 : (wc < 252 ? 1 : 2);
    return rh * 3 + rw;
}

// ---------------- kernel 0: weight convert/transpose to bf16, LN-gamma folded ----------------
// qkvT:[288][96] = g1[k]*qkv_w (q cols pre-scaled)   projT:[96][96]
// w1T:[384][96] = g2[k]*w1                           w2T:[96][384]
__global__ __launch_bounds__(256) void k_convert(
        const float* __restrict__ qkv_w, const float* __restrict__ proj_w,
        const float* __restrict__ w1, const float* __restrict__ w2,
        const float* __restrict__ n1g, const float* __restrict__ n2g,
        u16* __restrict__ qkvT, u16* __restrict__ projT,
        u16* __restrict__ w1T, u16* __restrict__ w2T) {
    int idx = blockIdx.x * 256 + threadIdx.x;
    if (idx < 288 * 96) {
        int n = idx / 96, k = idx % 96;
        float v = qkv_w[k * 288 + n] * n1g[k];
        if (n < 96) v *= SCALE;
        qkvT[n * 96 + k] = f2bf(v);
    }
    if (idx < 96 * 96) {
        int n = idx / 96, k = idx % 96;
        projT[n * 96 + k] = f2bf(proj_w[k * 96 + n]);
    }
    if (idx < 384 * 96) {
        int n = idx / 96, k = idx % 96;
        w1T[n * 96 + k] = f2bf(w1[k * 384 + n] * n2g[k]);
    }
    if (idx < 96 * 384) {
        int n = idx / 384, k = idx % 384;
        w2T[n * 384 + k] = f2bf(w2[k * 96 + n]);
    }
}

// ---------------- kernel 1: QKV GEMM with fused LN1 + roll + window partition ----------------
// 512 threads / 8 waves; each wave owns 16 rows -> acc[18] (72 VGPR) instead of
// acc[2][18] (144). __launch_bounds__(512,4) caps VGPR at 128 -> 4 waves/SIMD;
// LDS 61440 -> 2 blocks/CU -> 16 waves/CU (50% cap vs round-4's 25%/measured 11%).
__global__ __launch_bounds__(512, 4) void k_qkv(const float* __restrict__ x,
                                                const u16* __restrict__ wT,
                                                const float* __restrict__ qkv_wf,
                                                const float* __restrict__ qkv_b,
                                                const float* __restrict__ n1b,
                                                u16* __restrict__ qkv) {
    __shared__ __align__(16) u16 wlds[288 * 104];   // padded stride 104
    __shared__ float qb[288];
    {
        const int4* src = reinterpret_cast<const int4*>(wT);
        for (int i = threadIdx.x; i < 288 * 12; i += 512) {
            int row = i / 12, j = i - row * 12;
            *reinterpret_cast<int4*>(&wlds[row * 104 + j * 8]) = src[i];
        }
        if (threadIdx.x < 288) {
            int n = threadIdx.x;
            float s = qkv_b[n];
#pragma unroll 8
            for (int k = 0; k < 96; k++) s = fmaf(n1b[k], qkv_wf[k * 288 + n], s);
            qb[n] = (n < 96) ? s * SCALE : s;
        }
    }
    __syncthreads();
    const int wave = threadIdx.x >> 6, lane = threadIdx.x & 63;
    const int l15 = lane & 15, quad = lane >> 4;
    const int rowbase = blockIdx.x * 128 + wave * 16;
    // fused LN1 for this wave's 16 rows: A-frag lanes of one row live in the 4
    // quads -> cross-quad shfl_xor(16/32) gives row stats.
    bf16x8 afr[3];
    {
        int wtok = rowbase + l15;
        int win = wtok >> 6, n = wtok & 63;
        int b_ = win >> 10, wh = (win >> 5) & 31, ww = win & 31;
        int h0 = (wh * 8 + (n >> 3) + 4) & 255;
        int w0 = (ww * 8 + (n & 7) + 4) & 255;
        const float* row = x + ((size_t)(b_ * 256 + h0) * 256 + w0) * 96;
        float v[3][8];
        float s = 0.f, q = 0.f;
#pragma unroll
        for (int kb = 0; kb < 3; kb++) {
            f32x4 p0 = *reinterpret_cast<const f32x4*>(row + kb * 32 + quad * 8);
            f32x4 p1 = *reinterpret_cast<const f32x4*>(row + kb * 32 + quad * 8 + 4);
#pragma unroll
            for (int j = 0; j < 4; j++) { v[kb][j] = p0[j]; v[kb][4 + j] = p1[j]; }
#pragma unroll
            for (int j = 0; j < 8; j++) { s += v[kb][j]; q += v[kb][j] * v[kb][j]; }
        }
        s += __shfl_xor(s, 16); q += __shfl_xor(q, 16);
        s += __shfl_xor(s, 32); q += __shfl_xor(q, 32);
        float mean = s * (1.0f / 96.0f);
        float var  = q * (1.0f / 96.0f) - mean * mean;
        float rstd = rsqrtf(var + 1e-5f);
#pragma unroll
        for (int kb = 0; kb < 3; kb++) {
            union { bf16x8 f; u16 u[8]; } pk;
#pragma unroll
            for (int j = 0; j < 8; j++) pk.u[j] = f2bf((v[kb][j] - mean) * rstd);
            afr[kb] = pk.f;
        }
    }
    f32x4 zero = {0.f, 0.f, 0.f, 0.f};
    f32x4 acc[18];
#pragma unroll
    for (int ct = 0; ct < 18; ct++) acc[ct] = zero;
#pragma unroll
    for (int kb = 0; kb < 3; kb++) {
#pragma unroll
        for (int ct = 0; ct < 18; ct++) {
            bf16x8 bf = ldfrag(&wlds[(ct * 16 + l15) * 104 + kb * 32 + quad * 8]);
            acc[ct] = __builtin_amdgcn_mfma_f32_16x16x32_bf16(afr[kb], bf, acc[ct], 0, 0, 0);
        }
    }
#pragma unroll
    for (int ct = 0; ct < 18; ct++) {
        int col = ct * 16 + l15;
        float bv = qb[col];
#pragma unroll
        for (int r = 0; r < 4; r++) {
            int row = rowbase + quad * 4 + r;
            qkv[(size_t)row * 288 + col] = f2bf(acc[ct][r] + bv);
        }
    }
}

// ---------------- kernel 2: windowed attention (1 block/window, 1 wave/head) ----------------
__global__ __launch_bounds__(256) void k_attn(const u16* __restrict__ qkv,
                                              const float* __restrict__ btab,
                                              u16* __restrict__ aout) {
    __shared__ __align__(16) float blds[900];
    __shared__ __align__(16) u16 vt[4][24 * 72];   // V^T per head, padded stride 72
    __shared__ __align__(16) u16 pm[4][64 * 72];   // P per head, padded stride 72
    const int tid = threadIdx.x;
    for (int i = tid; i < 900; i += 256)
        blds[i] = fminf(fmaxf(btab[i], -5.0f), 5.0f);
    const int head = tid >> 6, lane = tid & 63;
    const int l15 = lane & 15, quad = lane >> 4;
    const int win = blockIdx.x;
    const int wh = (win >> 5) & 31, ww = win & 31;
    const u16* base = qkv + (size_t)win * 64 * 288;
    // stage V^T: vt[head][d][tok]
#pragma unroll
    for (int it = 0; it < 3; it++) {
        int idx = it * 64 + lane;
        int tok = idx / 3, ch = idx - tok * 3;
        int4 raw = *reinterpret_cast<const int4*>(base + tok * 288 + 192 + head * 24 + ch * 8);
        union { int4 v; u16 u[8]; } uu; uu.v = raw;
#pragma unroll
        for (int j = 0; j < 8; j++) vt[head][(ch * 8 + j) * 72 + tok] = uu.u[j];
    }
    __syncthreads();
    // Q (A-op) and K (B-op) fragments; K-dim 24 padded to 32 (quad 3 = zeros)
    bf16x8 aq[4], bk[4];
#pragma unroll
    for (int t = 0; t < 4; t++) {
        if (quad < 3) {
            aq[t] = ldfrag(base + (t * 16 + l15) * 288 + head * 24 + quad * 8);
            bk[t] = ldfrag(base + (t * 16 + l15) * 288 + 96 + head * 24 + quad * 8);
        } else { aq[t] = zfrag(); bk[t] = zfrag(); }
    }
    f32x4 zero = {0.f, 0.f, 0.f, 0.f};
    f32x4 s[4][4];
#pragma unroll
    for (int mt = 0; mt < 4; mt++)
#pragma unroll
        for (int ct = 0; ct < 4; ct++)
            s[mt][ct] = __builtin_amdgcn_mfma_f32_16x16x32_bf16(aq[mt], bk[ct], zero, 0, 0, 0);
    // per-column region ids for this lane
    int regc[4], colr[4], colc[4];
#pragma unroll
    for (int ct = 0; ct < 4; ct++) {
        int col = ct * 16 + l15;
        colr[ct] = col >> 3; colc[ct] = col & 7;
        regc[ct] = region_of(wh, ww, col);
    }
    // mask + bias + clip + row softmax (rows live in 16-lane groups)
#pragma unroll
    for (int mt = 0; mt < 4; mt++) {
#pragma unroll
        for (int r = 0; r < 4; r++) {
            int row = mt * 16 + quad * 4 + r;
            int rr = row >> 3, rc = row & 7;
            int regr = region_of(wh, ww, row);
            float sv[4]; float mx = -1e30f;
#pragma unroll
            for (int ct = 0; ct < 4; ct++) {
                float bias = blds[((rr - colr[ct] + 7) * 15 + (rc - colc[ct] + 7)) * 4 + head];
                float v = (regr == regc[ct])
                        ? fminf(fmaxf(s[mt][ct][r] + bias, -10.0f), 10.0f) : -10.0f;
                sv[ct] = v; mx = fmaxf(mx, v);
            }
#pragma unroll
            for (int m = 1; m < 16; m <<= 1) mx = fmaxf(mx, __shfl_xor(mx, m));
            float sum = 0.f;
#pragma unroll
            for (int ct = 0; ct < 4; ct++) { sv[ct] = __expf(sv[ct] - mx); sum += sv[ct]; }
#pragma unroll
            for (int m = 1; m < 16; m <<= 1) sum += __shfl_xor(sum, m);
            float inv = 1.0f / sum;
#pragma unroll
            for (int ct = 0; ct < 4; ct++)
                pm[head][row * 72 + ct * 16 + l15] = f2bf(sv[ct] * inv);
        }
    }
    __syncthreads();
    // O = P @ V
    f32x4 o[4][2];
#pragma unroll
    for (int mt = 0; mt < 4; mt++) { o[mt][0] = zero; o[mt][1] = zero; }
#pragma unroll
    for (int kb = 0; kb < 2; kb++) {
        bf16x8 ap[4];
#pragma unroll
        for (int mt = 0; mt < 4; mt++)
            ap[mt] = ldfrag(&pm[head][(mt * 16 + l15) * 72 + kb * 32 + quad * 8]);
        bf16x8 bv0 = ldfrag(&vt[head][l15 * 72 + kb * 32 + quad * 8]);
        bf16x8 bv1 = (l15 < 8) ? ldfrag(&vt[head][(16 + l15) * 72 + kb * 32 + quad * 8]) : zfrag();
#pragma unroll
        for (int mt = 0; mt < 4; mt++) {
            o[mt][0] = __builtin_amdgcn_mfma_f32_16x16x32_bf16(ap[mt], bv0, o[mt][0], 0, 0, 0);
            o[mt][1] = __builtin_amdgcn_mfma_f32_16x16x32_bf16(ap[mt], bv1, o[mt][1], 0, 0, 0);
        }
    }
#pragma unroll
    for (int ct2 = 0; ct2 < 2; ct2++) {
        int d = ct2 * 16 + l15;
        if (d < 24) {
#pragma unroll
            for (int mt = 0; mt < 4; mt++)
#pragma unroll
                for (int r = 0; r < 4; r++) {
                    int tok = mt * 16 + quad * 4 + r;
                    aout[((size_t)win * 64 + tok) * 96 + head * 24 + d] = f2bf(o[mt][ct2][r]);
                }
        }
    }
}

// ------- kernel 3: proj GEMM + window reverse + roll(+4,+4) + residual -> x1b (bf16) -------
// (LN2 lives in k_mlp)
__global__ __launch_bounds__(256) void k_proj(const u16* __restrict__ aout,
                                              const u16* __restrict__ wT,
                                              const float* __restrict__ pb,
                                              const float* __restrict__ x,
                                              u16* __restrict__ x1b) {
    __shared__ __align__(16) u16 wlds[96 * 104];
    {
        const int4* src = reinterpret_cast<const int4*>(wT);
        for (int i = threadIdx.x; i < 96 * 12; i += 256) {
            int row = i / 12, j = i - row * 12;
            *reinterpret_cast<int4*>(&wlds[row * 104 + j * 8]) = src[i];
        }
    }
    __syncthreads();
    const int wave = threadIdx.x >> 6, lane = threadIdx.x & 63;
    const int l15 = lane & 15, quad = lane >> 4;
    const int rowbase = blockIdx.x * 128 + wave * 32;
    f32x4 zero = {0.f, 0.f, 0.f, 0.f};
    f32x4 acc[2][6];
#pragma unroll
    for (int mt = 0; mt < 2; mt++)
#pragma unroll
        for (int ct = 0; ct < 6; ct++) acc[mt][ct] = zero;
#pragma unroll
    for (int kb = 0; kb < 96; kb += 32) {
        bf16x8 a0 = ldfrag(aout + (size_t)(rowbase + l15) * 96 + kb + quad * 8);
        bf16x8 a1 = ldfrag(aout + (size_t)(rowbase + 16 + l15) * 96 + kb + quad * 8);
#pragma unroll
        for (int ct = 0; ct < 6; ct++) {
            bf16x8 bf = ldfrag(&wlds[(ct * 16 + l15) * 104 + kb + quad * 8]);
            acc[0][ct] = __builtin_amdgcn_mfma_f32_16x16x32_bf16(a0, bf, acc[0][ct], 0, 0, 0);
            acc[1][ct] = __builtin_amdgcn_mfma_f32_16x16x32_bf16(a1, bf, acc[1][ct], 0, 0, 0);
        }
    }
    float pbv[6];
#pragma unroll
    for (int ct = 0; ct < 6; ct++) pbv[ct] = pb[ct * 16 + l15];
#pragma unroll
    for (int mt = 0; mt < 2; mt++)
#pragma unroll
        for (int r = 0; r < 4; r++) {
            int wtok = rowbase + mt * 16 + quad * 4 + r;
            int win = wtok >> 6, n = wtok & 63;
            int b_ = win >> 10, wh = (win >> 5) & 31, ww = win & 31;
            int h0 = (wh * 8 + (n >> 3) + 4) & 255;
            int w0 = (ww * 8 + (n & 7) + 4) & 255;
            size_t obase = ((size_t)(b_ * 256 + h0) * 256 + w0) * 96;
#pragma unroll
            for (int ct = 0; ct < 6; ct++) {
                size_t o = obase + ct * 16 + l15;
                x1b[o] = f2bf(acc[mt][ct][r] + pbv[ct] + x[o]);
            }
        }
}

// ------- kernel 4: fused MLP with in-register LN2, 16 waves, shuffle handoff -------
// LN2 affine folded: w1T pre-multiplied by g2; b1l[n] = b1[n] + sum_k n2b[k]*w1[k][n]
// (computed per block from L2-resident w1). A-frags (raw-normalized x1) register-resident
// across the whole kc loop -> x1 read ONCE per g. No barriers in main loop.
__global__ __launch_bounds__(1024) void k_mlp(const u16* __restrict__ x1,
                                              const float* __restrict__ b1,
                                              const float* __restrict__ n2b,
                                              const float* __restrict__ w1f,
                                              const u16* __restrict__ w1T,
                                              const u16* __restrict__ w2T,
                                              const float* __restrict__ b2,
                                              float* __restrict__ out) {
    __shared__ __align__(16) u16 w1l[384 * 104];   // 79872 B
    __shared__ __align__(16) u16 w2l[96 * 392];    // 75264 B
    __shared__ __align__(16) float b1l[384];       // 1536 B
    const int tid = threadIdx.x;
    {
        const int4* s1 = reinterpret_cast<const int4*>(w1T);
        for (int i = tid; i < 384 * 12; i += 1024) {
            int row = i / 12, j = i - row * 12;
            *reinterpret_cast<int4*>(&w1l[row * 104 + j * 8]) = s1[i];
        }
        const int4* s2 = reinterpret_cast<const int4*>(w2T);
        for (int i = tid; i < 96 * 48; i += 1024) {
            int row = i / 48, j = i - row * 48;
            *reinterpret_cast<int4*>(&w2l[row * 392 + j * 8]) = s2[i];
        }
        if (tid < 384) {
            float s = b1[tid];
#pragma unroll 8
            for (int k = 0; k < 96; k++) s = fmaf(n2b[k], w1f[k * 384 + tid], s);
            b1l[tid] = s;
        }
    }
    __syncthreads();   // the ONLY barrier
    const int wave = tid >> 6, lane = tid & 63;
    const int l15 = lane & 15, quad = lane >> 4;
    const int sA = ((lane & 16) << 1) + l15;
    const int sB = sA + 16;
    const bool useHi = (lane & 32) != 0;
    const f32x4 zero = {0.f, 0.f, 0.f, 0.f};
    float b2v[6];
#pragma unroll
    for (int ct2 = 0; ct2 < 6; ct2++) b2v[ct2] = b2[ct2 * 16 + l15];
#pragma unroll 1
    for (int g = 0; g < 4; ++g) {
        const int tok0 = blockIdx.x * 2048 + g * 512 + wave * 32;
        // in-register LN2 -> A-frags for gemm1 (held across the whole kc loop)
        bf16x8 a1[2][3];
#pragma unroll
        for (int m = 0; m < 2; m++) {
            const u16* rp = x1 + (size_t)(tok0 + m * 16 + l15) * 96;
            float v[3][8];
            float s = 0.f, q = 0.f;
#pragma unroll
            for (int kb = 0; kb < 3; kb++) {
                union { int4 i; u16 u[8]; } raw;
                raw.i = *reinterpret_cast<const int4*>(rp + kb * 32 + quad * 8);
#pragma unroll
                for (int j = 0; j < 8; j++) {
                    float f = bf2f(raw.u[j]);
                    v[kb][j] = f; s += f; q += f * f;
                }
            }
            s += __shfl_xor(s, 16); q += __shfl_xor(q, 16);
            s += __shfl_xor(s, 32); q += __shfl_xor(q, 32);
            float mean = s * (1.0f / 96.0f);
            float var  = q * (1.0f / 96.0f) - mean * mean;
            float rstd = rsqrtf(var + 1e-5f);
#pragma unroll
            for (int kb = 0; kb < 3; kb++) {
                union { bf16x8 f; u16 u[8]; } pk;
#pragma unroll
                for (int j = 0; j < 8; j++) pk.u[j] = f2bf((v[kb][j] - mean) * rstd);
                a1[m][kb] = pk.f;
            }
        }
        f32x4 acc2[2][6];
#pragma unroll
        for (int m = 0; m < 2; m++)
#pragma unroll
            for (int ct2 = 0; ct2 < 6; ct2++) acc2[m][ct2] = zero;
#pragma unroll 1
        for (int kc = 0; kc < 12; ++kc) {
            bf16x8 bw2[6];
#pragma unroll
            for (int ct2 = 0; ct2 < 6; ct2++)
                bw2[ct2] = ldfrag(&w2l[(ct2 * 16 + l15) * 392 + kc * 32 + quad * 8]);
            f32x4 bia0 = *reinterpret_cast<const f32x4*>(&b1l[kc * 32 + quad * 4]);
            f32x4 bia1 = *reinterpret_cast<const f32x4*>(&b1l[kc * 32 + 16 + quad * 4]);
            // gemm1 (swapped): D[h][t], lane holds t = l15, regs r -> h = kc*32 + ct*16 + quad*4 + r
            f32x4 acc1[2][2];
#pragma unroll
            for (int m = 0; m < 2; m++) { acc1[m][0] = zero; acc1[m][1] = zero; }
#pragma unroll
            for (int kb = 0; kb < 3; kb++) {
                bf16x8 wb0 = ldfrag(&w1l[(kc * 32 + l15) * 104 + kb * 32 + quad * 8]);
                bf16x8 wb1 = ldfrag(&w1l[(kc * 32 + 16 + l15) * 104 + kb * 32 + quad * 8]);
                acc1[0][0] = __builtin_amdgcn_mfma_f32_16x16x32_bf16(wb0, a1[0][kb], acc1[0][0], 0, 0, 0);
                acc1[0][1] = __builtin_amdgcn_mfma_f32_16x16x32_bf16(wb1, a1[0][kb], acc1[0][1], 0, 0, 0);
                acc1[1][0] = __builtin_amdgcn_mfma_f32_16x16x32_bf16(wb0, a1[1][kb], acc1[1][0], 0, 0, 0);
                acc1[1][1] = __builtin_amdgcn_mfma_f32_16x16x32_bf16(wb1, a1[1][kb], acc1[1][1], 0, 0, 0);
            }
#pragma unroll
            for (int m = 0; m < 2; m++) {
                // bias + GELU, pack (ct0, ct1) pairs into u32
                u32 p[4];
#pragma unroll
                for (int r = 0; r < 4; r++) {
                    float g0 = gelu_f(acc1[m][0][r] + bia0[r]);
                    float g1 = gelu_f(acc1[m][1][r] + bia1[r]);
                    p[r] = (u32)f2bf(g0) | ((u32)f2bf(g1) << 16);
                }
                // regroup to gemm2 A-layout: af[j] = H[t][kc*32 + quad*8 + j]
                u32 shl[4], shh[4];
#pragma unroll
                for (int r = 0; r < 4; r++) {
                    shl[r] = (u32)__shfl((int)p[r], sA);
                    shh[r] = (u32)__shfl((int)p[r], sB);
                }
                u32 aw[4];
                aw[0] = useHi ? ((shl[0] >> 16) | (shl[1] & 0xffff0000u))
                              : ((shl[0] & 0xffffu) | (shl[1] << 16));
                aw[1] = useHi ? ((shl[2] >> 16) | (shl[3] & 0xffff0000u))
                              : ((shl[2] & 0xffffu) | (shl[3] << 16));
                aw[2] = useHi ? ((shh[0] >> 16) | (shh[1] & 0xffff0000u))
                              : ((shh[0] & 0xffffu) | (shh[1] << 16));
                aw[3] = useHi ? ((shh[2] >> 16) | (shh[3] & 0xffff0000u))
                              : ((shh[2] & 0xffffu) | (shh[3] << 16));
                bf16x8 a2 = __builtin_bit_cast(bf16x8, *reinterpret_cast<uint4*>(aw));
#pragma unroll
                for (int ct2 = 0; ct2 < 6; ct2++)
                    acc2[m][ct2] = __builtin_amdgcn_mfma_f32_16x16x32_bf16(a2, bw2[ct2], acc2[m][ct2], 0, 0, 0);
            }
        }
        // epilogue: +b2, +residual, f32 store
#pragma unroll
        for (int m = 0; m < 2; m++)
#pragma unroll
            for (int ct2 = 0; ct2 < 6; ct2++)
#pragma unroll
                for (int r = 0; r < 4; r++) {
                    size_t o = (size_t)(tok0 + m * 16 + quad * 4 + r) * 96 + ct2 * 16 + l15;
                    out[o] = acc2[m][ct2][r] + b2v[ct2] + bf2f(x1[o]);
                }
    }
}

extern "C" void kernel_launch(void* const* d_in, const int* in_sizes, int n_in,
                              void* d_out, int out_size, void* d_ws, size_t ws_size,
                              hipStream_t stream) {
    const float* x      = (const float*)d_in[0];
    const float* n1g    = (const float*)d_in[1];
    const float* n1b    = (const float*)d_in[2];
    const float* qkv_w  = (const float*)d_in[3];
    const float* qkv_b  = (const float*)d_in[4];
    const float* btab   = (const float*)d_in[5];
    const float* proj_w = (const float*)d_in[6];
    const float* proj_b = (const float*)d_in[7];
    const float* n2g    = (const float*)d_in[8];
    const float* n2b    = (const float*)d_in[9];
    const float* w1     = (const float*)d_in[10];
    const float* b1     = (const float*)d_in[11];
    const float* w2     = (const float*)d_in[12];
    const float* b2     = (const float*)d_in[13];
    float* out = (float*)d_out;
    char* ws = (char*)d_ws;

    // region 0 (0..302MB): qkvb during qkv/attn phase; then x1b (bf16) after
    u16* qkvb  = (u16*)(ws);                  // 524288*288*2 = 301,989,888
    u16* x1b   = (u16*)(ws);                  // 100,663,296 (reuses qkvb after attn)
    u16* tokb  = (u16*)(ws + 301989888);      // 100,663,296 (attn out)
    u16* qkvT  = (u16*)(ws + 402653184);      // 288*96*2 = 55,296
    u16* projT = (u16*)(ws + 402708480);      // 96*96*2  = 18,432
    u16* w1T   = (u16*)(ws + 402726912);      // 384*96*2 = 73,728
    u16* w2T   = (u16*)(ws + 402800640);      // 96*384*2 = 73,728 (end 402,874,368)

    k_convert<<<144, 256, 0, stream>>>(qkv_w, proj_w, w1, w2, n1g, n2g, qkvT, projT, w1T, w2T);
    k_qkv<<<NTOK / 128, 512, 0, stream>>>(x, qkvT, qkv_w, qkv_b, n1b, qkvb);
    k_attn<<<NWIN, 256, 0, stream>>>(qkvb, btab, tokb);
    k_proj<<<NTOK / 128, 256, 0, stream>>>(tokb, projT, proj_b, x, x1b);
    k_mlp<<<256, 1024, 0, stream>>>(x1b, b1, n2b, w1, w1T, w2T, b2, out);
}